// Round 1
// baseline (685.501 us; speedup 1.0000x reference)
//
#include <hip/hip_runtime.h>
#include <hip/hip_bf16.h>
#include <math.h>

// Problem shape (from reference setup_inputs): B=1024, N=256, D=512, fp32.
// out = log(pos + neg) - log(pos)
//   pos = sum_b exp(dot(normalize(img[b]), fg_pro[b]))
//   neg = sum_{b,n} exp(dot(normalize(img[b]), bg_pro[b][n]))
// Memory-bound: bg_pro = 512 MiB streamed once -> ~86 us floor at 6.3 TB/s.

#define D_DIM 512

__device__ __forceinline__ float wave_reduce_sum(float x) {
    // 64-lane wave on CDNA
    #pragma unroll
    for (int off = 32; off > 0; off >>= 1)
        x += __shfl_xor(x, off);
    return x;
}

__global__ __launch_bounds__(256) void infonce_main(
    const float* __restrict__ img,     // [B, D]
    const float* __restrict__ fg_pro,  // [B, D]
    const float* __restrict__ bg_pro,  // [B, N, D]
    float* __restrict__ accum,         // accum[0]=pos_sum, accum[1]=neg_sum
    int N)
{
    const int b    = blockIdx.x;
    const int tid  = threadIdx.x;          // 0..255
    const int wid  = tid >> 6;             // wave id 0..3
    const int lane = tid & 63;

    __shared__ float s_img[D_DIM];         // normalized image row
    __shared__ float s_red[8];

    // ---- 1. load img[b], compute sum of squares (each thread: 2 floats) ----
    const float2 v = reinterpret_cast<const float2*>(img + (size_t)b * D_DIM)[tid];
    float ss = v.x * v.x + v.y * v.y;
    ss = wave_reduce_sum(ss);
    if (lane == 0) s_red[wid] = ss;
    __syncthreads();
    const float sumsq = s_red[0] + s_red[1] + s_red[2] + s_red[3];
    const float inv   = rsqrtf(sumsq);

    // ---- 2. normalized row -> LDS; pos dot with fg_pro[b] ----
    const float2 nv = make_float2(v.x * inv, v.y * inv);
    reinterpret_cast<float2*>(s_img)[tid] = nv;

    const float2 p = reinterpret_cast<const float2*>(fg_pro + (size_t)b * D_DIM)[tid];
    float pd = nv.x * p.x + nv.y * p.y;
    pd = wave_reduce_sum(pd);
    if (lane == 0) s_red[4 + wid] = pd;    // distinct slots: no race with s_red[0..3] readers
    __syncthreads();                        // covers s_img writes + s_red[4..7]
    if (tid == 0) {
        const float pos = s_red[4] + s_red[5] + s_red[6] + s_red[7];
        atomicAdd(&accum[0], expf(pos));
    }

    // ---- 3. bg logits: each wave strides rows n = wid, wid+4, ... ----
    const float4* s_img4 = reinterpret_cast<const float4*>(s_img);
    const float4  a0 = s_img4[lane];        // d = 4*lane      (0..255)
    const float4  a1 = s_img4[64 + lane];   // d = 256+4*lane  (256..511)

    const float4* bg4 = reinterpret_cast<const float4*>(bg_pro + (size_t)b * N * D_DIM);
    float local = 0.0f;
    for (int n = wid; n < N; n += 4) {
        const float4* row = bg4 + (size_t)n * (D_DIM / 4);
        const float4 b0 = row[lane];        // coalesced 16B/lane
        const float4 b1 = row[64 + lane];
        float dot = a0.x * b0.x + a0.y * b0.y + a0.z * b0.z + a0.w * b0.w
                  + a1.x * b1.x + a1.y * b1.y + a1.z * b1.z + a1.w * b1.w;
        dot = wave_reduce_sum(dot);
        if (lane == 0) local += expf(dot);
    }
    if (lane == 0) s_red[wid] = local;      // distinct from s_red[4..7] read above
    __syncthreads();
    if (tid == 0)
        atomicAdd(&accum[1], s_red[0] + s_red[1] + s_red[2] + s_red[3]);
}

__global__ void infonce_finalize(const float* __restrict__ accum,
                                 float* __restrict__ out)
{
    const float pos = accum[0];
    const float neg = accum[1];
    // -log(pos / (pos + neg))
    out[0] = logf(pos + neg) - logf(pos);
}

extern "C" void kernel_launch(void* const* d_in, const int* in_sizes, int n_in,
                              void* d_out, int out_size, void* d_ws, size_t ws_size,
                              hipStream_t stream)
{
    const float* img = (const float*)d_in[0];   // [B, D]
    const float* fg  = (const float*)d_in[1];   // [B, D]
    const float* bg  = (const float*)d_in[2];   // [B, N, D]
    float* out   = (float*)d_out;
    float* accum = (float*)d_ws;                // 2 floats

    const int B = in_sizes[0] / D_DIM;
    const int N = in_sizes[2] / in_sizes[0];

    hipMemsetAsync(accum, 0, 2 * sizeof(float), stream);
    infonce_main<<<B, 256, 0, stream>>>(img, fg, bg, accum, N);
    infonce_finalize<<<1, 1, 0, stream>>>(accum, out);
}

// Round 2
// 679.402 us; speedup vs baseline: 1.0090x; 1.0090x over previous
//
#include <hip/hip_runtime.h>
#include <hip/hip_bf16.h>
#include <math.h>

// Problem shape: B=1024, N=256, D=512, fp32.
// out = log(pos + neg) - log(pos)
//   pos = sum_b exp(dot(normalize(img[b]), fg_pro[b]))
//   neg = sum_{b,n} exp(dot(normalize(img[b]), bg_pro[b][n]))
// Memory-bound: bg_pro = 512 MiB streamed once -> ~86 us floor at 6.3 TB/s.
//
// R2: 2 blocks per b (2048 blocks -> 32 waves/CU), row-loop unrolled x4 so
// 8 float4 loads issue before the 4 interleaved butterfly reduces.

#define D_DIM   512
#define NSPLIT  2          // blocks per batch row

__global__ __launch_bounds__(256) void infonce_main(
    const float* __restrict__ img,     // [B, D]
    const float* __restrict__ fg_pro,  // [B, D]
    const float* __restrict__ bg_pro,  // [B, N, D]
    float* __restrict__ accum,         // accum[0]=pos_sum, accum[1]=neg_sum
    int N)
{
    const int b     = blockIdx.x >> 1;        // NSPLIT == 2
    const int split = blockIdx.x & 1;
    const int tid   = threadIdx.x;            // 0..255
    const int wid   = tid >> 6;               // wave 0..3
    const int lane  = tid & 63;

    __shared__ float s_img[D_DIM];            // normalized image row
    __shared__ float s_red[8];

    // ---- 1. load img[b], sum of squares (2 floats/thread) ----
    const float2 v = reinterpret_cast<const float2*>(img + (size_t)b * D_DIM)[tid];
    float ss = v.x * v.x + v.y * v.y;
    #pragma unroll
    for (int off = 32; off > 0; off >>= 1) ss += __shfl_xor(ss, off);
    if (lane == 0) s_red[wid] = ss;
    __syncthreads();
    const float inv = rsqrtf(s_red[0] + s_red[1] + s_red[2] + s_red[3]);

    // ---- 2. normalized row -> LDS; pos dot (split 0 only) ----
    const float2 nv = make_float2(v.x * inv, v.y * inv);
    reinterpret_cast<float2*>(s_img)[tid] = nv;

    if (split == 0) {
        const float2 p = reinterpret_cast<const float2*>(fg_pro + (size_t)b * D_DIM)[tid];
        float pd = nv.x * p.x + nv.y * p.y;
        #pragma unroll
        for (int off = 32; off > 0; off >>= 1) pd += __shfl_xor(pd, off);
        if (lane == 0) s_red[4 + wid] = pd;
    }
    __syncthreads();                          // covers s_img + s_red[4..7]
    if (split == 0 && tid == 0) {
        const float pos = s_red[4] + s_red[5] + s_red[6] + s_red[7];
        atomicAdd(&accum[0], expf(pos));
    }

    // ---- 3. bg rows: this block owns rows [split*N/2, split*N/2 + N/2) ----
    // wave wid takes a contiguous chunk of (N/NSPLIT/4) rows, unrolled x4.
    const int rows_per_block = N / NSPLIT;            // 128
    const int rows_per_wave  = rows_per_block / 4;    // 32
    const int n0 = split * rows_per_block + wid * rows_per_wave;

    const float4* s_img4 = reinterpret_cast<const float4*>(s_img);
    const float4  a0 = s_img4[lane];          // d = 4*lane
    const float4  a1 = s_img4[64 + lane];     // d = 256 + 4*lane

    const float4* bg4 = reinterpret_cast<const float4*>(bg_pro + (size_t)b * N * D_DIM);
    float local = 0.0f;

    for (int i = 0; i < rows_per_wave; i += 4) {
        const float4* r0 = bg4 + (size_t)(n0 + i + 0) * (D_DIM / 4);
        const float4* r1 = bg4 + (size_t)(n0 + i + 1) * (D_DIM / 4);
        const float4* r2 = bg4 + (size_t)(n0 + i + 2) * (D_DIM / 4);
        const float4* r3 = bg4 + (size_t)(n0 + i + 3) * (D_DIM / 4);
        // 8 independent 16B loads issue before any use
        const float4 b00 = r0[lane], b01 = r0[64 + lane];
        const float4 b10 = r1[lane], b11 = r1[64 + lane];
        const float4 b20 = r2[lane], b21 = r2[64 + lane];
        const float4 b30 = r3[lane], b31 = r3[64 + lane];

        float d0 = a0.x*b00.x + a0.y*b00.y + a0.z*b00.z + a0.w*b00.w
                 + a1.x*b01.x + a1.y*b01.y + a1.z*b01.z + a1.w*b01.w;
        float d1 = a0.x*b10.x + a0.y*b10.y + a0.z*b10.z + a0.w*b10.w
                 + a1.x*b11.x + a1.y*b11.y + a1.z*b11.z + a1.w*b11.w;
        float d2 = a0.x*b20.x + a0.y*b20.y + a0.z*b20.z + a0.w*b20.w
                 + a1.x*b21.x + a1.y*b21.y + a1.z*b21.z + a1.w*b21.w;
        float d3 = a0.x*b30.x + a0.y*b30.y + a0.z*b30.z + a0.w*b30.w
                 + a1.x*b31.x + a1.y*b31.y + a1.z*b31.z + a1.w*b31.w;

        // 4 interleaved butterfly reduces (independent chains -> ILP)
        #pragma unroll
        for (int off = 32; off > 0; off >>= 1) {
            d0 += __shfl_xor(d0, off);
            d1 += __shfl_xor(d1, off);
            d2 += __shfl_xor(d2, off);
            d3 += __shfl_xor(d3, off);
        }
        if (lane == 0)
            local += expf(d0) + expf(d1) + expf(d2) + expf(d3);
    }

    if (lane == 0) s_red[wid] = local;
    __syncthreads();
    if (tid == 0)
        atomicAdd(&accum[1], s_red[0] + s_red[1] + s_red[2] + s_red[3]);
}

__global__ void infonce_finalize(const float* __restrict__ accum,
                                 float* __restrict__ out)
{
    const float pos = accum[0];
    const float neg = accum[1];
    out[0] = logf(pos + neg) - logf(pos);   // == -log(pos/(pos+neg))
}

extern "C" void kernel_launch(void* const* d_in, const int* in_sizes, int n_in,
                              void* d_out, int out_size, void* d_ws, size_t ws_size,
                              hipStream_t stream)
{
    const float* img = (const float*)d_in[0];   // [B, D]
    const float* fg  = (const float*)d_in[1];   // [B, D]
    const float* bg  = (const float*)d_in[2];   // [B, N, D]
    float* out   = (float*)d_out;
    float* accum = (float*)d_ws;                // 2 floats

    const int B = in_sizes[0] / D_DIM;
    const int N = in_sizes[2] / in_sizes[0];

    hipMemsetAsync(accum, 0, 2 * sizeof(float), stream);
    infonce_main<<<B * NSPLIT, 256, 0, stream>>>(img, fg, bg, accum, N);
    infonce_finalize<<<1, 1, 0, stream>>>(accum, out);
}

// Round 3
// 677.567 us; speedup vs baseline: 1.0117x; 1.0027x over previous
//
#include <hip/hip_runtime.h>
#include <hip/hip_bf16.h>
#include <math.h>

// Problem shape: B=1024, N=256, D=512, fp32.
// out = log(pos + neg) - log(pos)
//   pos = sum_b exp(dot(normalize(img[b]), fg_pro[b]))
//   neg = sum_{b,n} exp(dot(normalize(img[b]), bg_pro[b][n]))
// Memory-bound: bg_pro = 512 MiB streamed once -> ~86 us kernel floor at 6.3 TB/s.
//
// R3: decouple streaming from reduction. Phase 1 is a pure load+FMA stream
// (per-lane row partials held in a VGPR array, NO cross-lane ops / branches
// inside the load loop -> deep load pipelining). Phase 2 does all butterfly
// reduces + expf as a short tail. NSPLIT=4 -> 4096 blocks, 16 rows/wave.

#define D_DIM   512
#define NSPLIT  4                 // blocks per batch row
#define ROWS_PER_WAVE 16          // N / NSPLIT / 4 waves = 256/4/4

__global__ __launch_bounds__(256) void infonce_main(
    const float* __restrict__ img,     // [B, D]
    const float* __restrict__ fg_pro,  // [B, D]
    const float* __restrict__ bg_pro,  // [B, N, D]
    float* __restrict__ accum,         // accum[0]=pos_sum, accum[1]=neg_sum
    int N)
{
    const int b     = blockIdx.x >> 2;        // NSPLIT == 4
    const int split = blockIdx.x & 3;
    const int tid   = threadIdx.x;            // 0..255
    const int wid   = tid >> 6;               // wave 0..3
    const int lane  = tid & 63;

    __shared__ float s_img[D_DIM];            // normalized image row
    __shared__ float s_red[8];

    // ---- 1. load img[b], sum of squares (2 floats/thread) ----
    const float2 v = reinterpret_cast<const float2*>(img + (size_t)b * D_DIM)[tid];
    float ss = v.x * v.x + v.y * v.y;
    #pragma unroll
    for (int off = 32; off > 0; off >>= 1) ss += __shfl_xor(ss, off);
    if (lane == 0) s_red[wid] = ss;
    __syncthreads();
    const float inv = rsqrtf(s_red[0] + s_red[1] + s_red[2] + s_red[3]);

    // ---- 2. normalized row -> LDS; pos dot (split 0 only) ----
    const float2 nv = make_float2(v.x * inv, v.y * inv);
    reinterpret_cast<float2*>(s_img)[tid] = nv;

    if (split == 0) {
        const float2 p = reinterpret_cast<const float2*>(fg_pro + (size_t)b * D_DIM)[tid];
        float pd = nv.x * p.x + nv.y * p.y;
        #pragma unroll
        for (int off = 32; off > 0; off >>= 1) pd += __shfl_xor(pd, off);
        if (lane == 0) s_red[4 + wid] = pd;
    }
    __syncthreads();                          // covers s_img + s_red[4..7]
    if (split == 0 && tid == 0) {
        const float pos = s_red[4] + s_red[5] + s_red[6] + s_red[7];
        atomicAdd(&accum[0], expf(pos));
    }

    // ---- 3. phase 1: pure stream. Each lane accumulates 8-elem partials ----
    const int n0 = split * (N / NSPLIT) + wid * ROWS_PER_WAVE;

    const float4* s_img4 = reinterpret_cast<const float4*>(s_img);
    const float4  a0 = s_img4[lane];          // d = 4*lane
    const float4  a1 = s_img4[64 + lane];     // d = 256 + 4*lane

    const float4* bg4 = reinterpret_cast<const float4*>(
        bg_pro + (size_t)b * N * D_DIM + (size_t)n0 * D_DIM);

    float part[ROWS_PER_WAVE];                // per-lane partial dot per row

    #pragma unroll
    for (int i = 0; i < ROWS_PER_WAVE; i += 4) {
        const float4* r0 = bg4 + (size_t)(i + 0) * (D_DIM / 4);
        const float4* r1 = bg4 + (size_t)(i + 1) * (D_DIM / 4);
        const float4* r2 = bg4 + (size_t)(i + 2) * (D_DIM / 4);
        const float4* r3 = bg4 + (size_t)(i + 3) * (D_DIM / 4);
        const float4 b00 = r0[lane], b01 = r0[64 + lane];
        const float4 b10 = r1[lane], b11 = r1[64 + lane];
        const float4 b20 = r2[lane], b21 = r2[64 + lane];
        const float4 b30 = r3[lane], b31 = r3[64 + lane];

        part[i + 0] = a0.x*b00.x + a0.y*b00.y + a0.z*b00.z + a0.w*b00.w
                    + a1.x*b01.x + a1.y*b01.y + a1.z*b01.z + a1.w*b01.w;
        part[i + 1] = a0.x*b10.x + a0.y*b10.y + a0.z*b10.z + a0.w*b10.w
                    + a1.x*b11.x + a1.y*b11.y + a1.z*b11.z + a1.w*b11.w;
        part[i + 2] = a0.x*b20.x + a0.y*b20.y + a0.z*b20.z + a0.w*b20.w
                    + a1.x*b21.x + a1.y*b21.y + a1.z*b21.z + a1.w*b21.w;
        part[i + 3] = a0.x*b30.x + a0.y*b30.y + a0.z*b30.z + a0.w*b30.w
                    + a1.x*b31.x + a1.y*b31.y + a1.z*b31.z + a1.w*b31.w;
    }

    // ---- 4. phase 2: tail reduce (butterflies + expf, off the load path) ----
    float local = 0.0f;
    #pragma unroll
    for (int i = 0; i < ROWS_PER_WAVE; i += 4) {
        float d0 = part[i + 0], d1 = part[i + 1],
              d2 = part[i + 2], d3 = part[i + 3];
        #pragma unroll
        for (int off = 32; off > 0; off >>= 1) {
            d0 += __shfl_xor(d0, off);
            d1 += __shfl_xor(d1, off);
            d2 += __shfl_xor(d2, off);
            d3 += __shfl_xor(d3, off);
        }
        if (lane == 0)
            local += expf(d0) + expf(d1) + expf(d2) + expf(d3);
    }

    if (lane == 0) s_red[wid] = local;
    __syncthreads();
    if (tid == 0)
        atomicAdd(&accum[1], s_red[0] + s_red[1] + s_red[2] + s_red[3]);
}

__global__ void infonce_finalize(const float* __restrict__ accum,
                                 float* __restrict__ out)
{
    const float pos = accum[0];
    const float neg = accum[1];
    out[0] = logf(pos + neg) - logf(pos);   // == -log(pos/(pos+neg))
}

extern "C" void kernel_launch(void* const* d_in, const int* in_sizes, int n_in,
                              void* d_out, int out_size, void* d_ws, size_t ws_size,
                              hipStream_t stream)
{
    const float* img = (const float*)d_in[0];   // [B, D]
    const float* fg  = (const float*)d_in[1];   // [B, D]
    const float* bg  = (const float*)d_in[2];   // [B, N, D]
    float* out   = (float*)d_out;
    float* accum = (float*)d_ws;                // 2 floats

    const int B = in_sizes[0] / D_DIM;
    const int N = in_sizes[2] / in_sizes[0];

    hipMemsetAsync(accum, 0, 2 * sizeof(float), stream);
    infonce_main<<<B * NSPLIT, 256, 0, stream>>>(img, fg, bg, accum, N);
    infonce_finalize<<<1, 1, 0, stream>>>(accum, out);
}